// Round 1
// baseline (132.621 us; speedup 1.0000x reference)
//
#include <hip/hip_runtime.h>

#define L_ 8
#define B_ 16
#define D_ 1024
#define S_ 32              // split-K segments over the i (reduction) axis
#define SEG (D_ / S_)      // 32 rows of W per block

// Computes partial[s][b][j] = sum_{i in segment s} h[b][i] * W[b][i][j]
// Grid: B_*S_ blocks, 256 threads. Each thread owns 4 output columns (float4).
__global__ void layer_partial(const float* __restrict__ h,
                              const float* __restrict__ W,      // layer base: [B][D][D]
                              float* __restrict__ partial) {    // [S][B][D]
    const int blk = blockIdx.x;
    const int b = blk / S_;
    const int s = blk % S_;
    const int tid = threadIdx.x;

    __shared__ float hs[SEG];
    if (tid < SEG) hs[tid] = h[b * D_ + s * SEG + tid];
    __syncthreads();

    const float4* __restrict__ W4 =
        (const float4*)(W + (size_t)b * D_ * D_ + (size_t)s * SEG * D_);

    float4 acc = {0.f, 0.f, 0.f, 0.f};
#pragma unroll 8
    for (int i = 0; i < SEG; ++i) {
        const float hv = hs[i];
        const float4 w = W4[i * (D_ / 4) + tid];
        acc.x += hv * w.x;
        acc.y += hv * w.y;
        acc.z += hv * w.z;
        acc.w += hv * w.w;
    }

    float4* P4 = (float4*)(partial + (size_t)s * (B_ * D_) + (size_t)b * D_);
    P4[tid] = acc;
}

// out[t] = maskedRelu( sum_s partial[s][t] + bias[t] ), t over B*D
// Grid: 64 blocks x 256 threads.
__global__ void layer_reduce(const float* __restrict__ partial,  // [S][B*D]
                             const float* __restrict__ bias,     // layer base [B*D]
                             const int* __restrict__ mask,       // layer base [B*D]
                             float* __restrict__ hout) {
    const int t = blockIdx.x * blockDim.x + threadIdx.x;
    float acc = bias[t];
#pragma unroll
    for (int s = 0; s < S_; ++s) acc += partial[s * (B_ * D_) + t];
    if (mask[t]) acc = fmaxf(acc, 0.f);
    hout[t] = acc;
}

extern "C" void kernel_launch(void* const* d_in, const int* in_sizes, int n_in,
                              void* d_out, int out_size, void* d_ws, size_t ws_size,
                              hipStream_t stream) {
    const float* x  = (const float*)d_in[0];
    const float* W  = (const float*)d_in[1];
    const float* Bs = (const float*)d_in[2];
    const int*   M  = (const int*)d_in[3];
    float* out = (float*)d_out;

    float* partial = (float*)d_ws;                 // S*B*D floats = 2 MB
    float* hA = partial + (size_t)S_ * B_ * D_;    // B*D floats
    float* hB = hA + (size_t)B_ * D_;              // B*D floats

    const float* hin = x;
    for (int l = 0; l < L_; ++l) {
        layer_partial<<<B_ * S_, 256, 0, stream>>>(
            hin, W + (size_t)l * B_ * D_ * D_, partial);
        float* hout = (l == L_ - 1) ? out : ((l & 1) ? hB : hA);
        layer_reduce<<<64, 256, 0, stream>>>(
            partial, Bs + (size_t)l * B_ * D_, M + (size_t)l * B_ * D_, hout);
        hin = hout;
    }
}

// Round 2
// 122.406 us; speedup vs baseline: 1.0835x; 1.0835x over previous
//
#include <hip/hip_runtime.h>

#define L_ 8
#define B_ 16
#define D_ 1024
#define JT 32              // output-column tile per block
#define IG 8               // i-groups per block (tid >> 5)
#define ILEN (D_ / IG)     // 128 reduction rows per i-group

// One block computes out[b, jt*JT : (jt+1)*JT] with the FULL i-reduction.
// Grid: B_ * (D_/JT) = 512 blocks, 256 threads.
__global__ __launch_bounds__(256) void layer_full(
    const float* __restrict__ h,     // [B][D] input activations
    const float* __restrict__ W,     // layer base [B][D][D]
    const float* __restrict__ bias,  // layer base [B][D]
    const int*   __restrict__ mask,  // layer base [B][D]
    float* __restrict__ hout)        // [B][D]
{
    const int blk = blockIdx.x;
    const int b   = blk / (D_ / JT);
    const int jt  = blk % (D_ / JT);
    const int tid = threadIdx.x;
    const int jl  = tid & 31;        // lane within j-tile
    const int ig  = tid >> 5;        // i-group 0..7

    __shared__ float hs[D_];
    {   // cooperative float4 load of h[b,:] (256 threads x 16B = 4KB)
        const float4* h4 = (const float4*)(h + (size_t)b * D_);
        ((float4*)hs)[tid] = h4[tid];
    }
    __syncthreads();

    // Thread reads W[b][i][jt*JT + jl] for i in its group; 32 lanes -> one
    // contiguous 128B segment per row.
    const float* __restrict__ Wp =
        W + (size_t)b * D_ * D_ + (size_t)(ig * ILEN) * D_ + jt * JT + jl;
    const float* __restrict__ hp = hs + ig * ILEN;

    float acc = 0.f;
#pragma unroll 16
    for (int i = 0; i < ILEN; ++i) {
        acc += hp[i] * Wp[(size_t)i * D_];
    }

    __shared__ float red[IG][JT];
    red[ig][jl] = acc;
    __syncthreads();

    if (tid < JT) {
        const int t = b * D_ + jt * JT + tid;
        float s = bias[t];
#pragma unroll
        for (int g = 0; g < IG; ++g) s += red[g][tid];
        if (mask[t]) s = fmaxf(s, 0.f);
        hout[t] = s;
    }
}

extern "C" void kernel_launch(void* const* d_in, const int* in_sizes, int n_in,
                              void* d_out, int out_size, void* d_ws, size_t ws_size,
                              hipStream_t stream) {
    const float* x  = (const float*)d_in[0];
    const float* W  = (const float*)d_in[1];
    const float* Bs = (const float*)d_in[2];
    const int*   M  = (const int*)d_in[3];

    float* hA = (float*)d_ws;
    float* hB = hA + (size_t)B_ * D_;

    const float* hin = x;
    for (int l = 0; l < L_; ++l) {
        float* hout = (l == L_ - 1) ? (float*)d_out : ((l & 1) ? hB : hA);
        layer_full<<<B_ * (D_ / JT), 256, 0, stream>>>(
            hin,
            W  + (size_t)l * B_ * D_ * D_,
            Bs + (size_t)l * B_ * D_,
            M  + (size_t)l * B_ * D_,
            hout);
        hin = hout;
    }
}